// Round 5
// baseline (31.986 us; speedup 1.0000x reference)
//
#include <hip/hip_runtime.h>
#include <math.h>

#ifndef M_PI
#define M_PI 3.14159265358979323846
#endif

#define MA 768   // MAX_ATOMS
#define NB 8192  // batch
#define WS_STRIDE 20

// Full-wave (64-lane) sum via DPP on the VALU pipe (no DS traffic).
// rocPRIM sequence; the total lands in lane 63.
__device__ __forceinline__ float dpp_red_add(float v) {
    v += __int_as_float(__builtin_amdgcn_update_dpp(0, __float_as_int(v), 0x111, 0xf, 0xf, true)); // row_shr:1
    v += __int_as_float(__builtin_amdgcn_update_dpp(0, __float_as_int(v), 0x112, 0xf, 0xf, true)); // row_shr:2
    v += __int_as_float(__builtin_amdgcn_update_dpp(0, __float_as_int(v), 0x114, 0xf, 0xe, true)); // row_shr:4
    v += __int_as_float(__builtin_amdgcn_update_dpp(0, __float_as_int(v), 0x118, 0xf, 0xc, true)); // row_shr:8
    v += __int_as_float(__builtin_amdgcn_update_dpp(0, __float_as_int(v), 0x142, 0xa, 0xf, true)); // row_bcast:15
    v += __int_as_float(__builtin_amdgcn_update_dpp(0, __float_as_int(v), 0x143, 0xc, 0xf, true)); // row_bcast:31
    return v;
}

// Kernel A: ONE WAVE PER SAMPLE. Each lane owns 12 consecutive atoms =
// 9 float4 from X + 9 from Y, all 18 loads issued with no intervening
// branches (full-row read; invalid atoms masked in registers).
__global__ __launch_bounds__(256) void kabsch_reduce_kernel(
    const float* __restrict__ inp, const float* __restrict__ tgt,
    const int* __restrict__ natoms, float* __restrict__ ws)
{
    const int wave = threadIdx.x >> 6;
    const int lane = threadIdx.x & 63;
    const int b = blockIdx.x * 4 + wave;
    const int n = natoms[b];
    const float* __restrict__ X = inp + (size_t)b * (3 * MA);
    const float* __restrict__ Y = tgt + (size_t)b * (3 * MA);

    // 12 atoms/lane, contiguous: floats [36*lane, 36*lane+36)
    float ax[36], ay[36];
    {
        const float4* px = (const float4*)(X + 36 * lane);
        const float4* py = (const float4*)(Y + 36 * lane);
#pragma unroll
        for (int k = 0; k < 9; ++k) {
            *(float4*)&ax[4 * k] = px[k];
            *(float4*)&ay[4 * k] = py[k];
        }
    }

    float sx0 = 0.f, sx1 = 0.f, sx2 = 0.f;
    float sy0 = 0.f, sy1 = 0.f, sy2 = 0.f;
    float c00 = 0.f, c01 = 0.f, c02 = 0.f;
    float c10 = 0.f, c11 = 0.f, c12 = 0.f;
    float c20 = 0.f, c21 = 0.f, c22 = 0.f;
    float nx2 = 0.f, ny2 = 0.f;

    const int a0 = 12 * lane;
#pragma unroll
    for (int j = 0; j < 12; ++j) {
        const bool v = (a0 + j) < n;
        const float x0 = v ? ax[3 * j + 0] : 0.f;
        const float x1 = v ? ax[3 * j + 1] : 0.f;
        const float x2 = v ? ax[3 * j + 2] : 0.f;
        const float y0 = v ? ay[3 * j + 0] : 0.f;
        const float y1 = v ? ay[3 * j + 1] : 0.f;
        const float y2 = v ? ay[3 * j + 2] : 0.f;
        sx0 += x0; sx1 += x1; sx2 += x2;
        sy0 += y0; sy1 += y1; sy2 += y2;
        c00 = fmaf(x0, y0, c00); c01 = fmaf(x0, y1, c01); c02 = fmaf(x0, y2, c02);
        c10 = fmaf(x1, y0, c10); c11 = fmaf(x1, y1, c11); c12 = fmaf(x1, y2, c12);
        c20 = fmaf(x2, y0, c20); c21 = fmaf(x2, y1, c21); c22 = fmaf(x2, y2, c22);
        nx2 = fmaf(x0, x0, nx2); nx2 = fmaf(x1, x1, nx2); nx2 = fmaf(x2, x2, nx2);
        ny2 = fmaf(y0, y0, ny2); ny2 = fmaf(y1, y1, ny2); ny2 = fmaf(y2, y2, ny2);
    }

    sx0 = dpp_red_add(sx0); sx1 = dpp_red_add(sx1); sx2 = dpp_red_add(sx2);
    sy0 = dpp_red_add(sy0); sy1 = dpp_red_add(sy1); sy2 = dpp_red_add(sy2);
    c00 = dpp_red_add(c00); c01 = dpp_red_add(c01); c02 = dpp_red_add(c02);
    c10 = dpp_red_add(c10); c11 = dpp_red_add(c11); c12 = dpp_red_add(c12);
    c20 = dpp_red_add(c20); c21 = dpp_red_add(c21); c22 = dpp_red_add(c22);
    nx2 = dpp_red_add(nx2); ny2 = dpp_red_add(ny2);

    if (lane == 63) {
        float4* pw = (float4*)(ws + (size_t)b * WS_STRIDE);
        pw[0] = make_float4(sx0, sx1, sx2, sy0);
        pw[1] = make_float4(sy1, sy2, c00, c01);
        pw[2] = make_float4(c02, c10, c11, c12);
        pw[3] = make_float4(c20, c21, c22, nx2);
        pw[4] = make_float4(ny2, 0.f, 0.f, 0.f);
    }
}

// Kernel B: one thread per sample — centered R, 3x3 eigensolve, RMSD.
// f64 arithmetic for the products; fast f32 acos/cos for the trig.
__global__ __launch_bounds__(256) void kabsch_finish_kernel(
    const float* __restrict__ ws, const int* __restrict__ natoms,
    float* __restrict__ out)
{
    const int b = blockIdx.x * 256 + threadIdx.x;
    const int n = natoms[b];
    const double inv_n = 1.0 / (double)n;

    const float4* pw = (const float4*)(ws + (size_t)b * WS_STRIDE);
    float4 w0 = pw[0], w1 = pw[1], w2 = pw[2], w3 = pw[3], w4 = pw[4];
    const float sx0 = w0.x, sx1 = w0.y, sx2 = w0.z, sy0 = w0.w;
    const float sy1 = w1.x, sy2 = w1.y, c00 = w1.z, c01 = w1.w;
    const float c02 = w2.x, c10 = w2.y, c11 = w2.z, c12 = w2.w;
    const float c20 = w3.x, c21 = w3.y, c22 = w3.z, nx2 = w3.w;
    const float ny2 = w4.x;

    double R00 = (double)c00 - (double)sx0 * (double)sy0 * inv_n;
    double R01 = (double)c01 - (double)sx0 * (double)sy1 * inv_n;
    double R02 = (double)c02 - (double)sx0 * (double)sy2 * inv_n;
    double R10 = (double)c10 - (double)sx1 * (double)sy0 * inv_n;
    double R11 = (double)c11 - (double)sx1 * (double)sy1 * inv_n;
    double R12 = (double)c12 - (double)sx1 * (double)sy2 * inv_n;
    double R20 = (double)c20 - (double)sx2 * (double)sy0 * inv_n;
    double R21 = (double)c21 - (double)sx2 * (double)sy1 * inv_n;
    double R22 = (double)c22 - (double)sx2 * (double)sy2 * inv_n;
    double ex = (double)nx2 -
        ((double)sx0 * sx0 + (double)sx1 * sx1 + (double)sx2 * sx2) * inv_n;
    double ey = (double)ny2 -
        ((double)sy0 * sy0 + (double)sy1 * sy1 + (double)sy2 * sy2) * inv_n;

    // A = R^T R (symmetric PSD); eigenvalues are squared singular values
    double A00 = R00 * R00 + R10 * R10 + R20 * R20;
    double A11 = R01 * R01 + R11 * R11 + R21 * R21;
    double A22 = R02 * R02 + R12 * R12 + R22 * R22;
    double A01 = R00 * R01 + R10 * R11 + R20 * R21;
    double A02 = R00 * R02 + R10 * R12 + R20 * R22;
    double A12 = R01 * R02 + R11 * R12 + R21 * R22;

    double detR = R00 * (R11 * R22 - R12 * R21)
                - R01 * (R10 * R22 - R12 * R20)
                + R02 * (R10 * R21 - R11 * R20);

    double q = (A00 + A11 + A22) / 3.0;
    double p1 = A01 * A01 + A02 * A02 + A12 * A12;
    double b00 = A00 - q, b11 = A11 - q, b22 = A22 - q;
    double p2 = b00 * b00 + b11 * b11 + b22 * b22 + 2.0 * p1;
    double e0, e1, e2;
    if (p2 <= 0.0) {
        e0 = e1 = e2 = q;
    } else {
        double p = sqrt(p2 / 6.0);
        double ip = 1.0 / p;
        double B00 = b00 * ip, B11 = b11 * ip, B22 = b22 * ip;
        double B01 = A01 * ip, B02 = A02 * ip, B12 = A12 * ip;
        double detB = B00 * (B11 * B22 - B12 * B12)
                    - B01 * (B01 * B22 - B12 * B02)
                    + B02 * (B01 * B12 - B11 * B02);
        double r = 0.5 * detB;
        r = fmin(1.0, fmax(-1.0, r));
        // trig in f32: phi in [0, pi/3]; error into out is ~1e-5 (thr 5e-2)
        float phi = acosf((float)r) * (1.0f / 3.0f);
        float cA = __cosf(phi);
        float cC = __cosf(phi + (float)(2.0 * M_PI / 3.0));
        e0 = q + 2.0 * p * (double)cA;
        e2 = q + 2.0 * p * (double)cC;
        e1 = 3.0 * q - e0 - e2;
    }
    double s0 = sqrt(fmax(e0, 0.0));
    double s1 = sqrt(fmax(e1, 0.0));
    double s2 = sqrt(fmax(e2, 0.0));
    double d = (detR > 0.0) ? 1.0 : ((detR < 0.0) ? -1.0 : 0.0);
    double tr = s0 + s1 + d * s2;
    double e = ex + ey - 2.0 * tr;
    out[b] = (float)sqrt(fmax(e, 0.0) * inv_n + 1e-7);
}

extern "C" void kernel_launch(void* const* d_in, const int* in_sizes, int n_in,
                              void* d_out, int out_size, void* d_ws, size_t ws_size,
                              hipStream_t stream) {
    const float* inp = (const float*)d_in[0];
    const float* tgt = (const float*)d_in[1];
    const int* natoms = (const int*)d_in[2];
    float* out = (float*)d_out;
    float* ws = (float*)d_ws;
    (void)ws_size; (void)n_in; (void)in_sizes;
    kabsch_reduce_kernel<<<dim3(out_size / 4), dim3(256), 0, stream>>>(inp, tgt, natoms, ws);
    kabsch_finish_kernel<<<dim3(out_size / 256), dim3(256), 0, stream>>>(ws, natoms, out);
}

// Round 6
// 25.864 us; speedup vs baseline: 1.2367x; 1.2367x over previous
//
#include <hip/hip_runtime.h>
#include <math.h>

#ifndef M_PI
#define M_PI 3.14159265358979323846
#endif

#define MA 768   // MAX_ATOMS
#define NB 8192  // batch
#define WS_STRIDE 20

// Full-wave (64-lane) sum via DPP on the VALU pipe (no DS traffic).
// rocPRIM sequence; the total lands in lane 63.
__device__ __forceinline__ float dpp_red_add(float v) {
    v += __int_as_float(__builtin_amdgcn_update_dpp(0, __float_as_int(v), 0x111, 0xf, 0xf, true)); // row_shr:1
    v += __int_as_float(__builtin_amdgcn_update_dpp(0, __float_as_int(v), 0x112, 0xf, 0xf, true)); // row_shr:2
    v += __int_as_float(__builtin_amdgcn_update_dpp(0, __float_as_int(v), 0x114, 0xf, 0xe, true)); // row_shr:4
    v += __int_as_float(__builtin_amdgcn_update_dpp(0, __float_as_int(v), 0x118, 0xf, 0xc, true)); // row_shr:8
    v += __int_as_float(__builtin_amdgcn_update_dpp(0, __float_as_int(v), 0x142, 0xa, 0xf, true)); // row_bcast:15
    v += __int_as_float(__builtin_amdgcn_update_dpp(0, __float_as_int(v), 0x143, 0xc, 0xf, true)); // row_bcast:31
    return v;
}

// Kernel A: ONE WAVE PER SAMPLE, 12 atoms/lane. All 18 dwordx4 loads are
// issued in one exec-masked cluster (lane active iff its first atom < n),
// pinned by sched_barrier(0) so the scheduler cannot sink them; ~128 VGPR
// budget via __launch_bounds__(256,4) keeps all 18 results live at once.
__global__ __launch_bounds__(256, 4) void kabsch_reduce_kernel(
    const float* __restrict__ inp, const float* __restrict__ tgt,
    const int* __restrict__ natoms, float* __restrict__ ws)
{
    const int wave = threadIdx.x >> 6;
    const int lane = threadIdx.x & 63;
    const int b = blockIdx.x * 4 + wave;
    const int n = natoms[b];
    const float* __restrict__ X = inp + (size_t)b * (3 * MA);
    const float* __restrict__ Y = tgt + (size_t)b * (3 * MA);

    const int a0 = 12 * lane;  // this lane's first atom

    const float4 f4z = make_float4(0.f, 0.f, 0.f, 0.f);
    float4 vx[9], vy[9];
#pragma unroll
    for (int k = 0; k < 9; ++k) { vx[k] = f4z; vy[k] = f4z; }

    if (a0 < n) {  // exec-masked: tail lanes fetch nothing
        const float4* px = (const float4*)(X + 3 * a0);
        const float4* py = (const float4*)(Y + 3 * a0);
#pragma unroll
        for (int k = 0; k < 9; ++k) vx[k] = px[k];
#pragma unroll
        for (int k = 0; k < 9; ++k) vy[k] = py[k];
    }
    __builtin_amdgcn_sched_barrier(0);  // nothing crosses: all 18 loads issue first

    float ax[36], ay[36];
#pragma unroll
    for (int k = 0; k < 9; ++k) {
        *(float4*)&ax[4 * k] = vx[k];
        *(float4*)&ay[4 * k] = vy[k];
    }

    float sx0 = 0.f, sx1 = 0.f, sx2 = 0.f;
    float sy0 = 0.f, sy1 = 0.f, sy2 = 0.f;
    float c00 = 0.f, c01 = 0.f, c02 = 0.f;
    float c10 = 0.f, c11 = 0.f, c12 = 0.f;
    float c20 = 0.f, c21 = 0.f, c22 = 0.f;
    float nx2 = 0.f, ny2 = 0.f;

#pragma unroll
    for (int j = 0; j < 12; ++j) {
        const bool v = (a0 + j) < n;
        const float x0 = v ? ax[3 * j + 0] : 0.f;
        const float x1 = v ? ax[3 * j + 1] : 0.f;
        const float x2 = v ? ax[3 * j + 2] : 0.f;
        const float y0 = v ? ay[3 * j + 0] : 0.f;
        const float y1 = v ? ay[3 * j + 1] : 0.f;
        const float y2 = v ? ay[3 * j + 2] : 0.f;
        sx0 += x0; sx1 += x1; sx2 += x2;
        sy0 += y0; sy1 += y1; sy2 += y2;
        c00 = fmaf(x0, y0, c00); c01 = fmaf(x0, y1, c01); c02 = fmaf(x0, y2, c02);
        c10 = fmaf(x1, y0, c10); c11 = fmaf(x1, y1, c11); c12 = fmaf(x1, y2, c12);
        c20 = fmaf(x2, y0, c20); c21 = fmaf(x2, y1, c21); c22 = fmaf(x2, y2, c22);
        nx2 = fmaf(x0, x0, nx2); nx2 = fmaf(x1, x1, nx2); nx2 = fmaf(x2, x2, nx2);
        ny2 = fmaf(y0, y0, ny2); ny2 = fmaf(y1, y1, ny2); ny2 = fmaf(y2, y2, ny2);
    }

    sx0 = dpp_red_add(sx0); sx1 = dpp_red_add(sx1); sx2 = dpp_red_add(sx2);
    sy0 = dpp_red_add(sy0); sy1 = dpp_red_add(sy1); sy2 = dpp_red_add(sy2);
    c00 = dpp_red_add(c00); c01 = dpp_red_add(c01); c02 = dpp_red_add(c02);
    c10 = dpp_red_add(c10); c11 = dpp_red_add(c11); c12 = dpp_red_add(c12);
    c20 = dpp_red_add(c20); c21 = dpp_red_add(c21); c22 = dpp_red_add(c22);
    nx2 = dpp_red_add(nx2); ny2 = dpp_red_add(ny2);

    if (lane == 63) {
        float4* pw = (float4*)(ws + (size_t)b * WS_STRIDE);
        pw[0] = make_float4(sx0, sx1, sx2, sy0);
        pw[1] = make_float4(sy1, sy2, c00, c01);
        pw[2] = make_float4(c02, c10, c11, c12);
        pw[3] = make_float4(c20, c21, c22, nx2);
        pw[4] = make_float4(ny2, 0.f, 0.f, 0.f);
    }
}

// Kernel B: one thread per sample — centered R, 3x3 eigensolve, RMSD.
// f64 arithmetic for the products; fast f32 acos/cos for the trig.
__global__ __launch_bounds__(256) void kabsch_finish_kernel(
    const float* __restrict__ ws, const int* __restrict__ natoms,
    float* __restrict__ out)
{
    const int b = blockIdx.x * 256 + threadIdx.x;
    const int n = natoms[b];
    const double inv_n = 1.0 / (double)n;

    const float4* pw = (const float4*)(ws + (size_t)b * WS_STRIDE);
    float4 w0 = pw[0], w1 = pw[1], w2 = pw[2], w3 = pw[3], w4 = pw[4];
    const float sx0 = w0.x, sx1 = w0.y, sx2 = w0.z, sy0 = w0.w;
    const float sy1 = w1.x, sy2 = w1.y, c00 = w1.z, c01 = w1.w;
    const float c02 = w2.x, c10 = w2.y, c11 = w2.z, c12 = w2.w;
    const float c20 = w3.x, c21 = w3.y, c22 = w3.z, nx2 = w3.w;
    const float ny2 = w4.x;

    double R00 = (double)c00 - (double)sx0 * (double)sy0 * inv_n;
    double R01 = (double)c01 - (double)sx0 * (double)sy1 * inv_n;
    double R02 = (double)c02 - (double)sx0 * (double)sy2 * inv_n;
    double R10 = (double)c10 - (double)sx1 * (double)sy0 * inv_n;
    double R11 = (double)c11 - (double)sx1 * (double)sy1 * inv_n;
    double R12 = (double)c12 - (double)sx1 * (double)sy2 * inv_n;
    double R20 = (double)c20 - (double)sx2 * (double)sy0 * inv_n;
    double R21 = (double)c21 - (double)sx2 * (double)sy1 * inv_n;
    double R22 = (double)c22 - (double)sx2 * (double)sy2 * inv_n;
    double ex = (double)nx2 -
        ((double)sx0 * sx0 + (double)sx1 * sx1 + (double)sx2 * sx2) * inv_n;
    double ey = (double)ny2 -
        ((double)sy0 * sy0 + (double)sy1 * sy1 + (double)sy2 * sy2) * inv_n;

    // A = R^T R (symmetric PSD); eigenvalues are squared singular values
    double A00 = R00 * R00 + R10 * R10 + R20 * R20;
    double A11 = R01 * R01 + R11 * R11 + R21 * R21;
    double A22 = R02 * R02 + R12 * R12 + R22 * R22;
    double A01 = R00 * R01 + R10 * R11 + R20 * R21;
    double A02 = R00 * R02 + R10 * R12 + R20 * R22;
    double A12 = R01 * R02 + R11 * R12 + R21 * R22;

    double detR = R00 * (R11 * R22 - R12 * R21)
                - R01 * (R10 * R22 - R12 * R20)
                + R02 * (R10 * R21 - R11 * R20);

    double q = (A00 + A11 + A22) / 3.0;
    double p1 = A01 * A01 + A02 * A02 + A12 * A12;
    double b00 = A00 - q, b11 = A11 - q, b22 = A22 - q;
    double p2 = b00 * b00 + b11 * b11 + b22 * b22 + 2.0 * p1;
    double e0, e1, e2;
    if (p2 <= 0.0) {
        e0 = e1 = e2 = q;
    } else {
        double p = sqrt(p2 / 6.0);
        double ip = 1.0 / p;
        double B00 = b00 * ip, B11 = b11 * ip, B22 = b22 * ip;
        double B01 = A01 * ip, B02 = A02 * ip, B12 = A12 * ip;
        double detB = B00 * (B11 * B22 - B12 * B12)
                    - B01 * (B01 * B22 - B12 * B02)
                    + B02 * (B01 * B12 - B11 * B02);
        double r = 0.5 * detB;
        r = fmin(1.0, fmax(-1.0, r));
        // trig in f32: phi in [0, pi/3]; error into out is ~1e-5 (thr 5e-2)
        float phi = acosf((float)r) * (1.0f / 3.0f);
        float cA = __cosf(phi);
        float cC = __cosf(phi + (float)(2.0 * M_PI / 3.0));
        e0 = q + 2.0 * p * (double)cA;
        e2 = q + 2.0 * p * (double)cC;
        e1 = 3.0 * q - e0 - e2;
    }
    double s0 = sqrt(fmax(e0, 0.0));
    double s1 = sqrt(fmax(e1, 0.0));
    double s2 = sqrt(fmax(e2, 0.0));
    double d = (detR > 0.0) ? 1.0 : ((detR < 0.0) ? -1.0 : 0.0);
    double tr = s0 + s1 + d * s2;
    double e = ex + ey - 2.0 * tr;
    out[b] = (float)sqrt(fmax(e, 0.0) * inv_n + 1e-7);
}

extern "C" void kernel_launch(void* const* d_in, const int* in_sizes, int n_in,
                              void* d_out, int out_size, void* d_ws, size_t ws_size,
                              hipStream_t stream) {
    const float* inp = (const float*)d_in[0];
    const float* tgt = (const float*)d_in[1];
    const int* natoms = (const int*)d_in[2];
    float* out = (float*)d_out;
    float* ws = (float*)d_ws;
    (void)ws_size; (void)n_in; (void)in_sizes;
    kabsch_reduce_kernel<<<dim3(out_size / 4), dim3(256), 0, stream>>>(inp, tgt, natoms, ws);
    kabsch_finish_kernel<<<dim3(out_size / 256), dim3(256), 0, stream>>>(ws, natoms, out);
}